// Round 1
// baseline (87.389 us; speedup 1.0000x reference)
//
#include <hip/hip_runtime.h>

#define BLOCK    256
#define DC       8        // db chunks (grid.y)
#define CHUNKPTS 2048     // db points per block
#define STAGEPTS 512      // db points per LDS stage (16 KB packed)
#define NSTAGE   (CHUNKPTS / STAGEPTS)
#define NQ       16384

typedef _Float16 f16;
typedef __attribute__((ext_vector_type(8)))  _Float16 f16x8;
typedef __attribute__((ext_vector_type(16))) float    f32x16;

union Pack { f16 h[16]; uint4 u[2]; };
union U8   { uint4 u; f16x8 v; };

__device__ __forceinline__ void split(float v, f16& h, f16& l) {
    h = (f16)v;
    l = (f16)(v - (float)h);
}

// db-side K-row: B[k] = {ph(3), pl(3), ph(3), pl(3), n2h, n2l, 0, 0}
__device__ __forceinline__ Pack pack_db(float x, float y, float z) {
    f16 hx, lx, hy, ly, hz, lz, nh, nl;
    split(x, hx, lx); split(y, hy, ly); split(z, hz, lz);
    float n2 = fmaf(x, x, fmaf(y, y, z * z));
    split(n2, nh, nl);
    Pack p;
    p.h[0] = hx;  p.h[1] = hy;  p.h[2] = hz;
    p.h[3] = lx;  p.h[4] = ly;  p.h[5] = lz;
    p.h[6] = hx;  p.h[7] = hy;  p.h[8] = hz;
    p.h[9] = lx;  p.h[10] = ly; p.h[11] = lz;
    p.h[12] = nh; p.h[13] = nl; p.h[14] = (f16)0.f; p.h[15] = (f16)0.f;
    return p;
}

// query-side K-row: A[k] = {-2qh(3), -2qh(3), -2ql(3), -2ql(3), 1, 1, 0, 0}
// pairing with B gives  -2*(qh+ql).(ph+pl) + |p|^2  to ~2^-22 relative.
__device__ __forceinline__ Pack pack_q(float x, float y, float z) {
    f16 hx, lx, hy, ly, hz, lz;
    split(-2.f * x, hx, lx); split(-2.f * y, hy, ly); split(-2.f * z, hz, lz);
    Pack p;
    p.h[0] = hx; p.h[1] = hy; p.h[2] = hz;
    p.h[3] = hx; p.h[4] = hy; p.h[5] = hz;
    p.h[6] = lx; p.h[7] = ly; p.h[8] = lz;
    p.h[9] = lx; p.h[10] = ly; p.h[11] = lz;
    p.h[12] = (f16)1.f; p.h[13] = (f16)1.f; p.h[14] = (f16)0.f; p.h[15] = (f16)0.f;
    return p;
}

// One launch covers both chamfer directions (blockIdx.z).
// Each wave: 2 A-tiles (64 queries) in regs; block streams 2048 db points
// through LDS in 4 packed stages; per-chunk row-mins -> plain stores (no atomics).
__global__ __launch_bounds__(BLOCK) void chamfer_pass(
    const float* __restrict__ Xc, const float* __restrict__ Xt,
    float* __restrict__ part, float* __restrict__ out)
{
    __shared__ uint4 tile[STAGEPTS * 2];   // 512 pts * 32 B = 16 KB

    const int tid = threadIdx.x;
    if (blockIdx.x == 0 && blockIdx.y == 0 && blockIdx.z == 0 && tid == 0)
        out[0] = 0.0f;   // stream-ordered before reduce's atomicAdd

    const float* Xq = (blockIdx.z == 0) ? Xc : Xt;
    const float* Xd = (blockIdx.z == 0) ? Xt : Xc;

    const int lane = tid & 63;
    const int w    = tid >> 6;
    const int col  = lane & 31;   // A row / B col within tile
    const int ksel = lane >> 5;   // which K-half (k0..7 / k8..15)

    // ---- A fragments: 2 tiles x 32 queries, packed in-register ----
    const int qrowbase = blockIdx.x * BLOCK + w * 64;
    f16x8 a0, a1;
    {
        int r0 = qrowbase + col;
        Pack p0 = pack_q(Xq[3 * r0], Xq[3 * r0 + 1], Xq[3 * r0 + 2]);
        U8 s; s.u = ksel ? p0.u[1] : p0.u[0]; a0 = s.v;
        int r1 = r0 + 32;
        Pack p1 = pack_q(Xq[3 * r1], Xq[3 * r1 + 1], Xq[3 * r1 + 2]);
        s.u = ksel ? p1.u[1] : p1.u[0]; a1 = s.v;
    }

    f32x16 acc0, acc1, zacc;
#pragma unroll
    for (int r = 0; r < 16; ++r) { acc0[r] = 3.0e38f; acc1[r] = 3.0e38f; zacc[r] = 0.f; }

    const int dbase = blockIdx.y * CHUNKPTS;
    const char* ldsb = (const char*)tile + (col * 32 + ksel * 16);

    for (int s = 0; s < NSTAGE; ++s) {
        __syncthreads();   // previous stage's reads done
        {
            // pack 512 db points (thread handles pts tid and tid+256)
            const float* src = Xd + (size_t)(dbase + s * STAGEPTS) * 3;
#pragma unroll
            for (int c = 0; c < 2; ++c) {
                int p = tid + c * BLOCK;
                Pack pb = pack_db(src[3 * p], src[3 * p + 1], src[3 * p + 2]);
                tile[2 * p]     = pb.u[0];
                tile[2 * p + 1] = pb.u[1];
            }
        }
        __syncthreads();

#pragma unroll
        for (int bt = 0; bt < 16; bt += 2) {
            f16x8 b0 = *(const f16x8*)(ldsb + bt * 1024);
            f16x8 b1 = *(const f16x8*)(ldsb + bt * 1024 + 1024);
            f32x16 d0 = __builtin_amdgcn_mfma_f32_32x32x16_f16(a0, b0, zacc, 0, 0, 0);
            f32x16 d1 = __builtin_amdgcn_mfma_f32_32x32x16_f16(a0, b1, zacc, 0, 0, 0);
#pragma unroll
            for (int r = 0; r < 16; ++r)   // v_min3_f32
                acc0[r] = fminf(fminf(d0[r], d1[r]), acc0[r]);
            f32x16 e0 = __builtin_amdgcn_mfma_f32_32x32x16_f16(a1, b0, zacc, 0, 0, 0);
            f32x16 e1 = __builtin_amdgcn_mfma_f32_32x32x16_f16(a1, b1, zacc, 0, 0, 0);
#pragma unroll
            for (int r = 0; r < 16; ++r)
                acc1[r] = fminf(fminf(e0[r], e1[r]), acc1[r]);
        }
    }

    // ---- min over the 32 db-columns (xor-shuffles stay inside each half-wave) ----
#pragma unroll
    for (int r = 0; r < 16; ++r) {
        float v0 = acc0[r], v1 = acc1[r];
#pragma unroll
        for (int off = 1; off < 32; off <<= 1) {
            v0 = fminf(v0, __shfl_xor(v0, off, 64));
            v1 = fminf(v1, __shfl_xor(v1, off, 64));
        }
        if (col == 0) {
            // C/D layout (HW-verified): col=lane&31, row=(r&3)+8*(r>>2)+4*(lane>>5)
            int row = (r & 3) + 8 * (r >> 2) + 4 * ksel;
            int q0  = qrowbase + row;
            part[((size_t)blockIdx.z * NQ + q0) * DC + blockIdx.y]      = v0;
            part[((size_t)blockIdx.z * NQ + q0 + 32) * DC + blockIdx.y] = v1;
        }
    }
}

// 8-way min over chunks, add |q|^2 (recomputed from raw input), clamp, average.
__global__ __launch_bounds__(BLOCK) void chamfer_reduce(
    const float* __restrict__ part, const float* __restrict__ Xc,
    const float* __restrict__ Xt, float* __restrict__ out)
{
    __shared__ float red[4];
    int e = blockIdx.x * BLOCK + threadIdx.x;   // 0 .. 2*NQ-1

    const float4* pb = (const float4*)(part + (size_t)e * DC);
    float4 m0 = pb[0], m1 = pb[1];
    float mn = fminf(fminf(fminf(m0.x, m0.y), fminf(m0.z, m0.w)),
                     fminf(fminf(m1.x, m1.y), fminf(m1.z, m1.w)));

    const float* X = (e < NQ) ? Xc : Xt;
    int q = (e < NQ) ? e : e - NQ;
    float x = X[3 * q], y = X[3 * q + 1], z = X[3 * q + 2];
    float n2 = fmaf(x, x, fmaf(y, y, z * z));
    float s = fmaxf(mn + n2, 0.0f) * (1.0f / 16384.0f);

#pragma unroll
    for (int off = 32; off > 0; off >>= 1) s += __shfl_down(s, off, 64);
    int wv = threadIdx.x >> 6, ln = threadIdx.x & 63;
    if (ln == 0) red[wv] = s;
    __syncthreads();
    if (threadIdx.x == 0) atomicAdd(out, red[0] + red[1] + red[2] + red[3]);
}

extern "C" void kernel_launch(void* const* d_in, const int* in_sizes, int n_in,
                              void* d_out, int out_size, void* d_ws, size_t ws_size,
                              hipStream_t stream) {
    const float* Xc = (const float*)d_in[0];
    const float* Xt = (const float*)d_in[1];
    float* part = (float*)d_ws;          // 2 * 16384 * 8 floats = 1 MB
    float* out  = (float*)d_out;

    dim3 grid(NQ / BLOCK /*64*/, DC, 2); // 1024 blocks, 4 waves each
    chamfer_pass<<<grid, BLOCK, 0, stream>>>(Xc, Xt, part, out);
    chamfer_reduce<<<(2 * NQ) / BLOCK /*128*/, BLOCK, 0, stream>>>(part, Xc, Xt, out);
}